// Round 1
// baseline (3180.565 us; speedup 1.0000x reference)
//
#include <hip/hip_runtime.h>
#include <math.h>

// Problem constants
#define BB   4
#define CIN  512
#define DD   256
#define NP   1600      // tokens per image (40*40)
#define TT   (BB*NP)   // 6400 total tokens
#define FF   2048
#define NHH  8
#define HDD  32
#define NA   3
#define NC   80

// ---------------------------------------------------------------------------
// Transpose x [B][CIN][NP] -> xT [T][CIN]
// ---------------------------------------------------------------------------
__global__ void transpose_x_kernel(const float* __restrict__ x, float* __restrict__ xT) {
    __shared__ float tile[32][33];
    int b  = blockIdx.z;
    int c0 = blockIdx.x * 32;
    int n0 = blockIdx.y * 32;
    int tx = threadIdx.x, ty = threadIdx.y;
    #pragma unroll
    for (int j = 0; j < 32; j += 8) {
        tile[ty + j][tx] = x[b * CIN * NP + (c0 + ty + j) * NP + (n0 + tx)];
    }
    __syncthreads();
    #pragma unroll
    for (int j = 0; j < 32; j += 8) {
        xT[(size_t)(b * NP + n0 + ty + j) * CIN + (c0 + tx)] = tile[tx][ty + j];
    }
}

// ---------------------------------------------------------------------------
// Generic fp32 GEMM: C[M,Nc] = A[M,K] @ B[K,Nc] + bias (+bias2) (+residual), opt ReLU
// Requires M%64==0, Nc%64==0, K%16==0.
// ---------------------------------------------------------------------------
__global__ __launch_bounds__(256) void gemm_kernel(
        const float* __restrict__ A, const float* __restrict__ Bw,
        const float* __restrict__ bias, const float* __restrict__ bias2,
        const float* __restrict__ residual, float* __restrict__ C,
        int M, int Nc, int K, int do_relu)
{
    __shared__ float As[16][65];
    __shared__ float Bs[16][65];
    int tx = threadIdx.x, ty = threadIdx.y;
    int tid = ty * 16 + tx;
    int m0 = blockIdx.y * 64;
    int n0 = blockIdx.x * 64;

    float acc[4][4] = {};

    for (int k0 = 0; k0 < K; k0 += 16) {
        // A tile: 64x16
        #pragma unroll
        for (int i = 0; i < 4; i++) {
            int idx = tid + i * 256;
            int r = idx >> 4, c = idx & 15;
            As[c][r] = A[(size_t)(m0 + r) * K + (k0 + c)];
        }
        // B tile: 16x64
        #pragma unroll
        for (int i = 0; i < 4; i++) {
            int idx = tid + i * 256;
            int r = idx >> 6, c = idx & 63;
            Bs[r][c] = Bw[(size_t)(k0 + r) * Nc + (n0 + c)];
        }
        __syncthreads();
        #pragma unroll
        for (int kk = 0; kk < 16; kk++) {
            float a[4], b[4];
            #pragma unroll
            for (int i = 0; i < 4; i++) a[i] = As[kk][ty * 4 + i];
            #pragma unroll
            for (int j = 0; j < 4; j++) b[j] = Bs[kk][tx * 4 + j];
            #pragma unroll
            for (int i = 0; i < 4; i++)
                #pragma unroll
                for (int j = 0; j < 4; j++)
                    acc[i][j] += a[i] * b[j];
        }
        __syncthreads();
    }

    #pragma unroll
    for (int i = 0; i < 4; i++) {
        int m = m0 + ty * 4 + i;
        #pragma unroll
        for (int j = 0; j < 4; j++) {
            int n = n0 + tx * 4 + j;
            float v = acc[i][j] + bias[n];
            if (bias2) v += bias2[n];
            if (do_relu) v = fmaxf(v, 0.f);
            if (residual) v += residual[(size_t)m * Nc + n];
            C[(size_t)m * Nc + n] = v;
        }
    }
}

// ---------------------------------------------------------------------------
// LayerNorm: one block (256 threads) per row of [T, 256]
// ---------------------------------------------------------------------------
__global__ __launch_bounds__(256) void ln_kernel(
        const float* __restrict__ x, const float* __restrict__ s,
        const float* __restrict__ b, float* __restrict__ y)
{
    int row = blockIdx.x;
    int t = threadIdx.x;
    float v = x[(size_t)row * DD + t];
    float s1 = v, s2 = v * v;
    #pragma unroll
    for (int m = 32; m >= 1; m >>= 1) {
        s1 += __shfl_xor(s1, m, 64);
        s2 += __shfl_xor(s2, m, 64);
    }
    __shared__ float w1[4], w2[4];
    int lane = t & 63, wid = t >> 6;
    if (lane == 0) { w1[wid] = s1; w2[wid] = s2; }
    __syncthreads();
    float S1 = w1[0] + w1[1] + w1[2] + w1[3];
    float S2 = w2[0] + w2[1] + w2[2] + w2[3];
    float mean = S1 * (1.f / DD);
    float var  = S2 * (1.f / DD) - mean * mean;
    float inv  = rsqrtf(var + 1e-5f);
    y[(size_t)row * DD + t] = (v - mean) * inv * s[t] + b[t];
}

// ---------------------------------------------------------------------------
// Flash-style attention, fp32. 1 wave/block; lane = 1 query.
// grid: (NP/64, NH, B); q/k/v layout [T, 256] with head h at cols h*32..h*32+31
// ---------------------------------------------------------------------------
__global__ __launch_bounds__(64) void attn_kernel(
        const float* __restrict__ q, const float* __restrict__ k,
        const float* __restrict__ v, float* __restrict__ o)
{
    __shared__ float Ks[64][32];
    __shared__ float Vs[64][32];
    int i  = threadIdx.x;          // 0..63
    int qt = blockIdx.x;           // query tile
    int h  = blockIdx.y;
    int b  = blockIdx.z;
    int t  = b * NP + qt * 64 + i;
    const float scale = 0.17677669529663687f; // 1/sqrt(32)

    float qreg[HDD];
    #pragma unroll
    for (int d = 0; d < HDD; d++) qreg[d] = q[(size_t)t * DD + h * HDD + d] * scale;

    float mmax = -1e30f, l = 0.f;
    float acc[HDD] = {};

    for (int m0 = 0; m0 < NP; m0 += 64) {
        #pragma unroll
        for (int j = 0; j < 32; j++) {
            int idx = j * 64 + i;
            int r = idx >> 5, c = idx & 31;
            size_t src = (size_t)(b * NP + m0 + r) * DD + h * HDD + c;
            Ks[r][c] = k[src];
            Vs[r][c] = v[src];
        }
        __syncthreads();

        float sreg[64];
        float tmax = -1e30f;
        #pragma unroll 8
        for (int mm = 0; mm < 64; mm++) {
            float sum = 0.f;
            #pragma unroll
            for (int d = 0; d < HDD; d++) sum += qreg[d] * Ks[mm][d];
            sreg[mm] = sum;
            tmax = fmaxf(tmax, sum);
        }
        float nm = fmaxf(mmax, tmax);
        float f = __expf(mmax - nm);
        l *= f;
        #pragma unroll
        for (int d = 0; d < HDD; d++) acc[d] *= f;
        #pragma unroll 8
        for (int mm = 0; mm < 64; mm++) {
            float p = __expf(sreg[mm] - nm);
            l += p;
            #pragma unroll
            for (int d = 0; d < HDD; d++) acc[d] += p * Vs[mm][d];
        }
        mmax = nm;
        __syncthreads();
    }
    float invl = 1.f / l;
    #pragma unroll
    for (int d = 0; d < HDD; d++) o[(size_t)t * DD + h * HDD + d] = acc[d] * invl;
}

// ---------------------------------------------------------------------------
// Head layer 2: out = t1 @ w2 + b2, scattered into [B,NA,H,W,S] layout.
// One block (256 threads) per token; ncols = NA*S.
// ---------------------------------------------------------------------------
__global__ __launch_bounds__(256) void head2_kernel(
        const float* __restrict__ t1, const float* __restrict__ w2,
        const float* __restrict__ b2, float* __restrict__ out,
        int ncols, int S)
{
    __shared__ float row[DD];
    int token = blockIdx.x;
    int c = threadIdx.x;
    row[c] = t1[(size_t)token * DD + c];
    __syncthreads();
    if (c < ncols) {
        float sum = b2[c];
        #pragma unroll 8
        for (int kk = 0; kk < DD; kk++) sum += row[kk] * w2[kk * ncols + c];
        int a  = c / S;
        int s  = c - a * S;
        int b  = token / NP;
        int hw = token - b * NP;
        out[((size_t)(b * NA + a) * NP + hw) * S + s] = sum;
    }
}

// ---------------------------------------------------------------------------
static inline void launch_gemm(const float* A, const float* Bw, const float* bias,
                               const float* bias2, const float* res, float* C,
                               int M, int Nc, int K, int relu, hipStream_t s) {
    dim3 g(Nc / 64, M / 64), b(16, 16);
    hipLaunchKernelGGL(gemm_kernel, g, b, 0, s, A, Bw, bias, bias2, res, C, M, Nc, K, relu);
}

extern "C" void kernel_launch(void* const* d_in, const int* in_sizes, int n_in,
                              void* d_out, int out_size, void* d_ws, size_t ws_size,
                              hipStream_t stream) {
    const float* x      = (const float*)d_in[0];
    const float* conv_w = (const float*)d_in[1];
    const float* conv_b = (const float*)d_in[2];
    const float* pos    = (const float*)d_in[3];
    const float* qw     = (const float*)d_in[4];
    const float* qb     = (const float*)d_in[5];
    const float* kw     = (const float*)d_in[6];
    const float* kb     = (const float*)d_in[7];
    const float* vw     = (const float*)d_in[8];
    const float* vb     = (const float*)d_in[9];
    const float* pw     = (const float*)d_in[10];
    const float* pb     = (const float*)d_in[11];
    const float* ln1s   = (const float*)d_in[12];
    const float* ln1b   = (const float*)d_in[13];
    const float* ln2s   = (const float*)d_in[14];
    const float* ln2b   = (const float*)d_in[15];
    const float* f1w    = (const float*)d_in[16];
    const float* f1b    = (const float*)d_in[17];
    const float* f2w    = (const float*)d_in[18];
    const float* f2b    = (const float*)d_in[19];
    const float* cls_w1 = (const float*)d_in[20];
    const float* cls_b1 = (const float*)d_in[21];
    const float* cls_w2 = (const float*)d_in[22];
    const float* cls_b2 = (const float*)d_in[23];
    const float* box_w1 = (const float*)d_in[24];
    const float* box_b1 = (const float*)d_in[25];
    const float* box_w2 = (const float*)d_in[26];
    const float* box_b2 = (const float*)d_in[27];
    const float* obj_w1 = (const float*)d_in[28];
    const float* obj_b1 = (const float*)d_in[29];
    const float* obj_w2 = (const float*)d_in[30];
    const float* obj_b2 = (const float*)d_in[31];

    float* out = (float*)d_out;
    const size_t TD = (size_t)TT * DD;   // 1,638,400

    float* ws  = (float*)d_ws;
    float* h   = ws;
    float* y   = h  + TD;
    float* q   = y  + TD;
    float* kk  = q  + TD;
    float* vv  = kk + TD;
    float* o   = vv + TD;
    float* big = o  + TD;          // shared region: xT (3.28M) then ffn (13.1M)
    float* xT  = big;
    float* ffn = big;
    float* t1  = q;                // reuse q after transformer layers

    // 1) x transpose -> [T, CIN]
    hipLaunchKernelGGL(transpose_x_kernel, dim3(CIN / 32, NP / 32, BB), dim3(32, 8),
                       0, stream, x, xT);

    // 2) conv 1x1 projection + conv_b + pos  -> h [T, D]
    launch_gemm(xT, conv_w, conv_b, pos, nullptr, h, TT, DD, CIN, 0, stream);

    // 3) transformer layers
    for (int i = 0; i < 2; i++) {
        const float* qwi = qw + (size_t)i * DD * DD;
        const float* kwi = kw + (size_t)i * DD * DD;
        const float* vwi = vw + (size_t)i * DD * DD;
        const float* pwi = pw + (size_t)i * DD * DD;
        const float* f1wi = f1w + (size_t)i * DD * FF;
        const float* f2wi = f2w + (size_t)i * FF * DD;

        hipLaunchKernelGGL(ln_kernel, dim3(TT), dim3(DD), 0, stream,
                           h, ln1s + i * DD, ln1b + i * DD, y);
        launch_gemm(y, qwi, qb + i * DD, nullptr, nullptr, q,  TT, DD, DD, 0, stream);
        launch_gemm(y, kwi, kb + i * DD, nullptr, nullptr, kk, TT, DD, DD, 0, stream);
        launch_gemm(y, vwi, vb + i * DD, nullptr, nullptr, vv, TT, DD, DD, 0, stream);

        hipLaunchKernelGGL(attn_kernel, dim3(NP / 64, NHH, BB), dim3(64), 0, stream,
                           q, kk, vv, o);

        launch_gemm(o, pwi, pb + i * DD, nullptr, h, h, TT, DD, DD, 0, stream);

        hipLaunchKernelGGL(ln_kernel, dim3(TT), dim3(DD), 0, stream,
                           h, ln2s + i * DD, ln2b + i * DD, y);
        launch_gemm(y, f1wi, f1b + i * FF, nullptr, nullptr, ffn, TT, FF, DD, 1, stream);
        launch_gemm(ffn, f2wi, f2b + i * DD, nullptr, h, h, TT, DD, FF, 0, stream);
    }

    // 4) heads
    float* cls_out = out;
    float* box_out = out + (size_t)BB * NA * NP * NC;            // 1,536,000
    float* obj_out = box_out + (size_t)BB * NA * NP * 4;         // +76,800

    launch_gemm(h, cls_w1, cls_b1, nullptr, nullptr, t1, TT, DD, DD, 1, stream);
    hipLaunchKernelGGL(head2_kernel, dim3(TT), dim3(DD), 0, stream,
                       t1, cls_w2, cls_b2, cls_out, NA * NC, NC);

    launch_gemm(h, box_w1, box_b1, nullptr, nullptr, t1, TT, DD, DD, 1, stream);
    hipLaunchKernelGGL(head2_kernel, dim3(TT), dim3(DD), 0, stream,
                       t1, box_w2, box_b2, box_out, NA * 4, 4);

    launch_gemm(h, obj_w1, obj_b1, nullptr, nullptr, t1, TT, DD, DD, 1, stream);
    hipLaunchKernelGGL(head2_kernel, dim3(TT), dim3(DD), 0, stream,
                       t1, obj_w2, obj_b2, obj_out, NA * 1, 1);
}

// Round 2
// 1431.828 us; speedup vs baseline: 2.2213x; 2.2213x over previous
//
#include <hip/hip_runtime.h>
#include <math.h>

// Problem constants
#define BB   4
#define CIN  512
#define DD   256
#define NP   1600      // tokens per image (40*40)
#define TT   (BB*NP)   // 6400 total tokens
#define FF   2048
#define NHH  8
#define HDD  32
#define NA   3
#define NC   80

typedef __attribute__((ext_vector_type(8))) short bf16x8_t;
typedef __attribute__((ext_vector_type(4))) float f32x4_t;

static __device__ __forceinline__ ushort f2bf(float f) {
    unsigned int u = __float_as_uint(f);
    u += 0x7FFF + ((u >> 16) & 1);          // round-to-nearest-even
    return (ushort)(u >> 16);
}

// ---------------------------------------------------------------------------
// Transpose x [B][CIN][NP] -> xT [T][CIN]
// ---------------------------------------------------------------------------
__global__ void transpose_x_kernel(const float* __restrict__ x, float* __restrict__ xT) {
    __shared__ float tile[32][33];
    int b  = blockIdx.z;
    int c0 = blockIdx.x * 32;
    int n0 = blockIdx.y * 32;
    int tx = threadIdx.x, ty = threadIdx.y;
    #pragma unroll
    for (int j = 0; j < 32; j += 8) {
        tile[ty + j][tx] = x[b * CIN * NP + (c0 + ty + j) * NP + (n0 + tx)];
    }
    __syncthreads();
    #pragma unroll
    for (int j = 0; j < 32; j += 8) {
        xT[(size_t)(b * NP + n0 + ty + j) * CIN + (c0 + tx)] = tile[tx][ty + j];
    }
}

// ---------------------------------------------------------------------------
// Generic fp32 GEMM: C[M,Nc] = A[M,K] @ B[K,Nc] + bias (+bias2) (+residual),
// opt ReLU, opt bf16 output. Requires M%64==0, Nc%64==0, K%16==0.
// ---------------------------------------------------------------------------
__global__ __launch_bounds__(256) void gemm_kernel(
        const float* __restrict__ A, const float* __restrict__ Bw,
        const float* __restrict__ bias, const float* __restrict__ bias2,
        const float* __restrict__ residual, float* __restrict__ C,
        int M, int Nc, int K, int do_relu, int out_bf16)
{
    __shared__ float As[16][65];
    __shared__ float Bs[16][65];
    int tx = threadIdx.x, ty = threadIdx.y;
    int tid = ty * 16 + tx;
    int m0 = blockIdx.y * 64;
    int n0 = blockIdx.x * 64;

    float acc[4][4] = {};

    for (int k0 = 0; k0 < K; k0 += 16) {
        #pragma unroll
        for (int i = 0; i < 4; i++) {
            int idx = tid + i * 256;
            int r = idx >> 4, c = idx & 15;
            As[c][r] = A[(size_t)(m0 + r) * K + (k0 + c)];
        }
        #pragma unroll
        for (int i = 0; i < 4; i++) {
            int idx = tid + i * 256;
            int r = idx >> 6, c = idx & 63;
            Bs[r][c] = Bw[(size_t)(k0 + r) * Nc + (n0 + c)];
        }
        __syncthreads();
        #pragma unroll
        for (int kk = 0; kk < 16; kk++) {
            float a[4], b[4];
            #pragma unroll
            for (int i = 0; i < 4; i++) a[i] = As[kk][ty * 4 + i];
            #pragma unroll
            for (int j = 0; j < 4; j++) b[j] = Bs[kk][tx * 4 + j];
            #pragma unroll
            for (int i = 0; i < 4; i++)
                #pragma unroll
                for (int j = 0; j < 4; j++)
                    acc[i][j] += a[i] * b[j];
        }
        __syncthreads();
    }

    #pragma unroll
    for (int i = 0; i < 4; i++) {
        int m = m0 + ty * 4 + i;
        #pragma unroll
        for (int j = 0; j < 4; j++) {
            int n = n0 + tx * 4 + j;
            float v = acc[i][j] + bias[n];
            if (bias2) v += bias2[n];
            if (do_relu) v = fmaxf(v, 0.f);
            if (residual) v += residual[(size_t)m * Nc + n];
            if (out_bf16) ((ushort*)C)[(size_t)m * Nc + n] = f2bf(v);
            else          C[(size_t)m * Nc + n] = v;
        }
    }
}

// ---------------------------------------------------------------------------
// LayerNorm: one block (256 threads) per row of [T, 256]
// ---------------------------------------------------------------------------
__global__ __launch_bounds__(256) void ln_kernel(
        const float* __restrict__ x, const float* __restrict__ s,
        const float* __restrict__ b, float* __restrict__ y)
{
    int row = blockIdx.x;
    int t = threadIdx.x;
    float v = x[(size_t)row * DD + t];
    float s1 = v, s2 = v * v;
    #pragma unroll
    for (int m = 32; m >= 1; m >>= 1) {
        s1 += __shfl_xor(s1, m, 64);
        s2 += __shfl_xor(s2, m, 64);
    }
    __shared__ float w1[4], w2[4];
    int lane = t & 63, wid = t >> 6;
    if (lane == 0) { w1[wid] = s1; w2[wid] = s2; }
    __syncthreads();
    float S1 = w1[0] + w1[1] + w1[2] + w1[3];
    float S2 = w2[0] + w2[1] + w2[2] + w2[3];
    float mean = S1 * (1.f / DD);
    float var  = S2 * (1.f / DD) - mean * mean;
    float inv  = rsqrtf(var + 1e-5f);
    y[(size_t)row * DD + t] = (v - mean) * inv * s[t] + b[t];
}

// ---------------------------------------------------------------------------
// MFMA bf16 flash attention.
// Block = 256 thr = 4 waves; each wave owns 16 queries. KV tiles of 32 keys.
// q,k,v: bf16 [T][256] (head h at cols h*32..+31); o: fp32 [T][256].
// Swapped QK^T: S^T = mfma(K_frag, Q_frag) -> lane holds S^T[key=g*4+r][q=lane&15]
// so softmax stats and O^T accumulator share q = lane&15 (no layout clash).
// P goes through a tiny per-wave LDS tile to re-shape for the PV B-operand.
// No __syncthreads anywhere (per-wave LDS regions, in-order DS pipe).
// ---------------------------------------------------------------------------
__global__ __launch_bounds__(256) void attn_mfma_kernel(
        const ushort* __restrict__ q, const ushort* __restrict__ k,
        const ushort* __restrict__ v, float* __restrict__ o)
{
    __shared__ ushort P_lds[4][16][40];    // [wave][q][key], padded row=80B
    int lane = threadIdx.x & 63;
    int wid  = threadIdx.x >> 6;
    int qrow = lane & 15;                  // query index within wave tile
    int g    = lane >> 4;                  // lane group 0..3
    int h = blockIdx.y, b = blockIdx.z;
    int q0 = blockIdx.x * 64 + wid * 16;

    const float scale = 0.17677669529663687f;   // 1/sqrt(32)

    const size_t tq = (size_t)(b * NP + q0 + qrow) * DD + h * HDD;
    bf16x8_t qf = *(const bf16x8_t*)(q + tq + g * 8);   // Q[q0+qrow][g*8..+7]

    float m = -1e30f, lsum = 0.f;
    f32x4_t ot0 = {0.f, 0.f, 0.f, 0.f};    // O^T[d=g*4+r][q=qrow]
    f32x4_t ot1 = {0.f, 0.f, 0.f, 0.f};    // O^T[d=16+g*4+r][q=qrow]

    for (int k0 = 0; k0 < NP; k0 += 32) {
        // --- QK^T (swapped): 2 MFMAs give S^T for 32 keys x 16 queries
        const size_t kb = (size_t)(b * NP + k0 + qrow) * DD + h * HDD + g * 8;
        bf16x8_t kf0 = *(const bf16x8_t*)(k + kb);            // keys k0..k0+15
        bf16x8_t kf1 = *(const bf16x8_t*)(k + kb + 16 * DD);  // keys k0+16..+31
        f32x4_t z = {0.f, 0.f, 0.f, 0.f};
        f32x4_t s0 = __builtin_amdgcn_mfma_f32_16x16x32_bf16(kf0, qf, z, 0, 0, 0);
        f32x4_t s1 = __builtin_amdgcn_mfma_f32_16x16x32_bf16(kf1, qf, z, 0, 0, 0);

        float sv[8];
        #pragma unroll
        for (int r = 0; r < 4; r++) { sv[r] = s0[r] * scale; sv[4 + r] = s1[r] * scale; }

        // --- online softmax over this tile (per query = lane&15)
        float tmax = fmaxf(fmaxf(fmaxf(sv[0], sv[1]), fmaxf(sv[2], sv[3])),
                           fmaxf(fmaxf(sv[4], sv[5]), fmaxf(sv[6], sv[7])));
        tmax = fmaxf(tmax, __shfl_xor(tmax, 16, 64));
        tmax = fmaxf(tmax, __shfl_xor(tmax, 32, 64));
        float nm = fmaxf(m, tmax);
        float f  = __expf(m - nm);
        lsum *= f;
        #pragma unroll
        for (int r = 0; r < 4; r++) { ot0[r] *= f; ot1[r] *= f; }

        float psum = 0.f;
        ushort pb[8];
        #pragma unroll
        for (int i = 0; i < 8; i++) {
            float p = __expf(sv[i] - nm);
            psum += p;
            pb[i] = f2bf(p);
        }
        psum += __shfl_xor(psum, 16, 64);
        psum += __shfl_xor(psum, 32, 64);
        lsum += psum;
        m = nm;

        // --- P re-shape through LDS: write [q][key], read PV B-fragment
        *(ushort4*)&P_lds[wid][qrow][g * 4]      = make_ushort4(pb[0], pb[1], pb[2], pb[3]);
        *(ushort4*)&P_lds[wid][qrow][16 + g * 4] = make_ushort4(pb[4], pb[5], pb[6], pb[7]);
        bf16x8_t pf = *(const bf16x8_t*)&P_lds[wid][qrow][g * 8];

        // --- PV: O^T += V^T . P^T  (2 MFMAs, d-tiles 0..15 / 16..31)
        const ushort* vp = v + (size_t)(b * NP + k0) * DD + h * HDD;
        bf16x8_t va0, va1;
        #pragma unroll
        for (int j = 0; j < 8; j++) {
            const ushort* vr = vp + (size_t)(g * 8 + j) * DD;
            va0[j] = (short)vr[qrow];        // V[key][d=qrow]
            va1[j] = (short)vr[16 + qrow];   // V[key][d=16+qrow]
        }
        ot0 = __builtin_amdgcn_mfma_f32_16x16x32_bf16(va0, pf, ot0, 0, 0, 0);
        ot1 = __builtin_amdgcn_mfma_f32_16x16x32_bf16(va1, pf, ot1, 0, 0, 0);
    }

    float inv = 1.f / lsum;
    float4 r0 = make_float4(ot0[0] * inv, ot0[1] * inv, ot0[2] * inv, ot0[3] * inv);
    float4 r1 = make_float4(ot1[0] * inv, ot1[1] * inv, ot1[2] * inv, ot1[3] * inv);
    *(float4*)(o + tq + g * 4)      = r0;
    *(float4*)(o + tq + 16 + g * 4) = r1;
}

// ---------------------------------------------------------------------------
// Head layer 2: out = t1 @ w2 + b2, scattered into [B,NA,H,W,S] layout.
// ---------------------------------------------------------------------------
__global__ __launch_bounds__(256) void head2_kernel(
        const float* __restrict__ t1, const float* __restrict__ w2,
        const float* __restrict__ b2, float* __restrict__ out,
        int ncols, int S)
{
    __shared__ float row[DD];
    int token = blockIdx.x;
    int c = threadIdx.x;
    row[c] = t1[(size_t)token * DD + c];
    __syncthreads();
    if (c < ncols) {
        float sum = b2[c];
        #pragma unroll 8
        for (int kk = 0; kk < DD; kk++) sum += row[kk] * w2[kk * ncols + c];
        int a  = c / S;
        int s  = c - a * S;
        int b  = token / NP;
        int hw = token - b * NP;
        out[((size_t)(b * NA + a) * NP + hw) * S + s] = sum;
    }
}

// ---------------------------------------------------------------------------
static inline void launch_gemm(const float* A, const float* Bw, const float* bias,
                               const float* bias2, const float* res, float* C,
                               int M, int Nc, int K, int relu, int obf, hipStream_t s) {
    dim3 g(Nc / 64, M / 64), b(16, 16);
    hipLaunchKernelGGL(gemm_kernel, g, b, 0, s, A, Bw, bias, bias2, res, C, M, Nc, K, relu, obf);
}

extern "C" void kernel_launch(void* const* d_in, const int* in_sizes, int n_in,
                              void* d_out, int out_size, void* d_ws, size_t ws_size,
                              hipStream_t stream) {
    const float* x      = (const float*)d_in[0];
    const float* conv_w = (const float*)d_in[1];
    const float* conv_b = (const float*)d_in[2];
    const float* pos    = (const float*)d_in[3];
    const float* qw     = (const float*)d_in[4];
    const float* qb     = (const float*)d_in[5];
    const float* kw     = (const float*)d_in[6];
    const float* kb     = (const float*)d_in[7];
    const float* vw     = (const float*)d_in[8];
    const float* vb     = (const float*)d_in[9];
    const float* pw     = (const float*)d_in[10];
    const float* pb     = (const float*)d_in[11];
    const float* ln1s   = (const float*)d_in[12];
    const float* ln1b   = (const float*)d_in[13];
    const float* ln2s   = (const float*)d_in[14];
    const float* ln2b   = (const float*)d_in[15];
    const float* f1w    = (const float*)d_in[16];
    const float* f1b    = (const float*)d_in[17];
    const float* f2w    = (const float*)d_in[18];
    const float* f2b    = (const float*)d_in[19];
    const float* cls_w1 = (const float*)d_in[20];
    const float* cls_b1 = (const float*)d_in[21];
    const float* cls_w2 = (const float*)d_in[22];
    const float* cls_b2 = (const float*)d_in[23];
    const float* box_w1 = (const float*)d_in[24];
    const float* box_b1 = (const float*)d_in[25];
    const float* box_w2 = (const float*)d_in[26];
    const float* box_b2 = (const float*)d_in[27];
    const float* obj_w1 = (const float*)d_in[28];
    const float* obj_b1 = (const float*)d_in[29];
    const float* obj_w2 = (const float*)d_in[30];
    const float* obj_b2 = (const float*)d_in[31];

    float* out = (float*)d_out;
    const size_t TD = (size_t)TT * DD;   // 1,638,400

    float* ws  = (float*)d_ws;
    float* h   = ws;
    float* y   = h  + TD;
    float* q   = y  + TD;          // bf16 during attention phase
    float* kk  = q  + TD;          // bf16
    float* vv  = kk + TD;          // bf16
    float* o   = vv + TD;
    float* big = o  + TD;          // shared region: xT then ffn
    float* xT  = big;
    float* ffn = big;
    float* t1  = q;                // reuse q (fp32) after transformer layers

    // 1) x transpose -> [T, CIN]
    hipLaunchKernelGGL(transpose_x_kernel, dim3(CIN / 32, NP / 32, BB), dim3(32, 8),
                       0, stream, x, xT);

    // 2) conv 1x1 projection + conv_b + pos  -> h [T, D]
    launch_gemm(xT, conv_w, conv_b, pos, nullptr, h, TT, DD, CIN, 0, 0, stream);

    // 3) transformer layers
    for (int i = 0; i < 2; i++) {
        const float* qwi = qw + (size_t)i * DD * DD;
        const float* kwi = kw + (size_t)i * DD * DD;
        const float* vwi = vw + (size_t)i * DD * DD;
        const float* pwi = pw + (size_t)i * DD * DD;
        const float* f1wi = f1w + (size_t)i * DD * FF;
        const float* f2wi = f2w + (size_t)i * FF * DD;

        hipLaunchKernelGGL(ln_kernel, dim3(TT), dim3(DD), 0, stream,
                           h, ln1s + i * DD, ln1b + i * DD, y);
        launch_gemm(y, qwi, qb + i * DD, nullptr, nullptr, q,  TT, DD, DD, 0, 1, stream);
        launch_gemm(y, kwi, kb + i * DD, nullptr, nullptr, kk, TT, DD, DD, 0, 1, stream);
        launch_gemm(y, vwi, vb + i * DD, nullptr, nullptr, vv, TT, DD, DD, 0, 1, stream);

        hipLaunchKernelGGL(attn_mfma_kernel, dim3(NP / 64, NHH, BB), dim3(256), 0, stream,
                           (const ushort*)q, (const ushort*)kk, (const ushort*)vv, o);

        launch_gemm(o, pwi, pb + i * DD, nullptr, h, h, TT, DD, DD, 0, 0, stream);

        hipLaunchKernelGGL(ln_kernel, dim3(TT), dim3(DD), 0, stream,
                           h, ln2s + i * DD, ln2b + i * DD, y);
        launch_gemm(y, f1wi, f1b + i * FF, nullptr, nullptr, ffn, TT, FF, DD, 1, 0, stream);
        launch_gemm(ffn, f2wi, f2b + i * DD, nullptr, h, h, TT, DD, FF, 0, 0, stream);
    }

    // 4) heads
    float* cls_out = out;
    float* box_out = out + (size_t)BB * NA * NP * NC;
    float* obj_out = box_out + (size_t)BB * NA * NP * 4;

    launch_gemm(h, cls_w1, cls_b1, nullptr, nullptr, t1, TT, DD, DD, 1, 0, stream);
    hipLaunchKernelGGL(head2_kernel, dim3(TT), dim3(DD), 0, stream,
                       t1, cls_w2, cls_b2, cls_out, NA * NC, NC);

    launch_gemm(h, box_w1, box_b1, nullptr, nullptr, t1, TT, DD, DD, 1, 0, stream);
    hipLaunchKernelGGL(head2_kernel, dim3(TT), dim3(DD), 0, stream,
                       t1, box_w2, box_b2, box_out, NA * 4, 4);

    launch_gemm(h, obj_w1, obj_b1, nullptr, nullptr, t1, TT, DD, DD, 1, 0, stream);
    hipLaunchKernelGGL(head2_kernel, dim3(TT), dim3(DD), 0, stream,
                       t1, obj_w2, obj_b2, obj_out, NA * 1, 1);
}

// Round 3
// 452.175 us; speedup vs baseline: 7.0339x; 3.1665x over previous
//
#include <hip/hip_runtime.h>
#include <math.h>

// Problem constants
#define BB   4
#define CIN  512
#define DD   256
#define NP   1600      // tokens per image (40*40)
#define TT   (BB*NP)   // 6400 total tokens
#define FF   2048
#define NHH  8
#define HDD  32
#define NA   3
#define NC   80

typedef __attribute__((ext_vector_type(8))) short bf16x8_t;
typedef __attribute__((ext_vector_type(4))) float f32x4_t;
typedef __attribute__((ext_vector_type(16))) float f32x16_t;

static __device__ __forceinline__ ushort f2bf(float f) {
    unsigned int u = __float_as_uint(f);
    u += 0x7FFF + ((u >> 16) & 1);          // round-to-nearest-even
    return (ushort)(u >> 16);
}
static __device__ __forceinline__ float bf2f(ushort u) {
    return __uint_as_float((unsigned int)u << 16);
}

// ---------------------------------------------------------------------------
// Weight prep: batched transpose + fp32->bf16. src [R][C] f32 -> dst [C][R] bf16
// ---------------------------------------------------------------------------
struct WDesc { const float* src; ushort* dst; int R; int C; int ntiles; };
struct WPrep { WDesc d[16]; };

__global__ __launch_bounds__(256) void wprep_kernel(WPrep p) {
    __shared__ float tile[32][33];
    int t = blockIdx.x;
    int i = 0;
    while (t >= p.d[i].ntiles) { t -= p.d[i].ntiles; i++; }
    const float* src = p.d[i].src;
    ushort* dst = p.d[i].dst;
    int R = p.d[i].R, C = p.d[i].C;
    int tC = C >> 5;
    int r0 = (t / tC) * 32, c0 = (t % tC) * 32;
    int tx = threadIdx.x, ty = threadIdx.y;
    #pragma unroll
    for (int j = 0; j < 32; j += 8)
        tile[ty + j][tx] = src[(size_t)(r0 + ty + j) * C + (c0 + tx)];
    __syncthreads();
    #pragma unroll
    for (int j = 0; j < 32; j += 8)
        dst[(size_t)(c0 + ty + j) * R + (r0 + tx)] = f2bf(tile[tx][ty + j]);
}

// ---------------------------------------------------------------------------
// Transpose x [B][CIN][NP] f32 -> xT [T][CIN] bf16
// ---------------------------------------------------------------------------
__global__ void transpose_x_kernel(const float* __restrict__ x, ushort* __restrict__ xT) {
    __shared__ float tile[32][33];
    int b  = blockIdx.z;
    int c0 = blockIdx.x * 32;
    int n0 = blockIdx.y * 32;
    int tx = threadIdx.x, ty = threadIdx.y;
    #pragma unroll
    for (int j = 0; j < 32; j += 8) {
        tile[ty + j][tx] = x[b * CIN * NP + (c0 + ty + j) * NP + (n0 + tx)];
    }
    __syncthreads();
    #pragma unroll
    for (int j = 0; j < 32; j += 8) {
        xT[(size_t)(b * NP + n0 + ty + j) * CIN + (c0 + tx)] = f2bf(tile[tx][ty + j]);
    }
}

// ---------------------------------------------------------------------------
// MFMA bf16 GEMM: C[M,N] = A[M,K](bf16) @ Bt[N,K](bf16)^T + bias (+bias2)
// (+residual f32), opt ReLU. Outputs: Cf (f32) and/or Cbf (bf16).
// 64x64 tile, BK=64, 4 waves each computing one 32x32 mfma_32x32x16 fragment.
// ---------------------------------------------------------------------------
__global__ __launch_bounds__(256) void gemm_mfma_kernel(
        const ushort* __restrict__ A, const ushort* __restrict__ Bt,
        const float* __restrict__ bias, const float* __restrict__ bias2,
        const float* __restrict__ residual, float* __restrict__ Cf,
        ushort* __restrict__ Cbf, int M, int N, int K, int do_relu)
{
    __shared__ ushort As[64][72];   // 144B row stride (16B aligned)
    __shared__ ushort Bs[64][72];
    int tid  = threadIdx.x;
    int lane = tid & 63, wid = tid >> 6;
    int wm = wid >> 1, wn = wid & 1;
    int m0 = blockIdx.y * 64, n0 = blockIdx.x * 64;
    int ln31 = lane & 31, lg = lane >> 5;

    int srow = tid >> 2;            // 0..63
    int scol = (tid & 3) * 16;      // 0,16,32,48

    const ushort* ag = A  + (size_t)(m0 + srow) * K + scol;
    const ushort* bg = Bt + (size_t)(n0 + srow) * K + scol;

    f32x16_t acc = {};

    for (int k0 = 0; k0 < K; k0 += 64) {
        uint4 av0 = *(const uint4*)(ag + k0);
        uint4 av1 = *(const uint4*)(ag + k0 + 8);
        uint4 bv0 = *(const uint4*)(bg + k0);
        uint4 bv1 = *(const uint4*)(bg + k0 + 8);
        *(uint4*)&As[srow][scol]     = av0;
        *(uint4*)&As[srow][scol + 8] = av1;
        *(uint4*)&Bs[srow][scol]     = bv0;
        *(uint4*)&Bs[srow][scol + 8] = bv1;
        __syncthreads();
        #pragma unroll
        for (int kc = 0; kc < 4; kc++) {
            bf16x8_t af = *(const bf16x8_t*)&As[wm * 32 + ln31][kc * 16 + lg * 8];
            bf16x8_t bf = *(const bf16x8_t*)&Bs[wn * 32 + ln31][kc * 16 + lg * 8];
            acc = __builtin_amdgcn_mfma_f32_32x32x16_bf16(af, bf, acc, 0, 0, 0);
        }
        __syncthreads();
    }

    int n = n0 + wn * 32 + ln31;
    float bsum = bias[n] + (bias2 ? bias2[n] : 0.f);
    #pragma unroll
    for (int r = 0; r < 16; r++) {
        int row = (r & 3) + 8 * (r >> 2) + 4 * lg;
        int m = m0 + wm * 32 + row;
        float v = acc[r] + bsum;
        if (do_relu) v = fmaxf(v, 0.f);
        if (residual) v += residual[(size_t)m * N + n];
        if (Cf)  Cf [(size_t)m * N + n] = v;
        if (Cbf) Cbf[(size_t)m * N + n] = f2bf(v);
    }
}

// ---------------------------------------------------------------------------
// LayerNorm: one block (256 threads) per row of [T, 256]; f32 in, bf16 out
// ---------------------------------------------------------------------------
__global__ __launch_bounds__(256) void ln_kernel(
        const float* __restrict__ x, const float* __restrict__ s,
        const float* __restrict__ b, ushort* __restrict__ y)
{
    int row = blockIdx.x;
    int t = threadIdx.x;
    float v = x[(size_t)row * DD + t];
    float s1 = v, s2 = v * v;
    #pragma unroll
    for (int m = 32; m >= 1; m >>= 1) {
        s1 += __shfl_xor(s1, m, 64);
        s2 += __shfl_xor(s2, m, 64);
    }
    __shared__ float w1[4], w2[4];
    int lane = t & 63, wid = t >> 6;
    if (lane == 0) { w1[wid] = s1; w2[wid] = s2; }
    __syncthreads();
    float S1 = w1[0] + w1[1] + w1[2] + w1[3];
    float S2 = w2[0] + w2[1] + w2[2] + w2[3];
    float mean = S1 * (1.f / DD);
    float var  = S2 * (1.f / DD) - mean * mean;
    float inv  = rsqrtf(var + 1e-5f);
    y[(size_t)row * DD + t] = f2bf((v - mean) * inv * s[t] + b[t]);
}

// ---------------------------------------------------------------------------
// MFMA bf16 flash attention (bf16 in, bf16 out). 4 waves/block, 16 q/wave.
// ---------------------------------------------------------------------------
__global__ __launch_bounds__(256) void attn_mfma_kernel(
        const ushort* __restrict__ q, const ushort* __restrict__ k,
        const ushort* __restrict__ v, ushort* __restrict__ o)
{
    __shared__ ushort P_lds[4][16][40];
    int lane = threadIdx.x & 63;
    int wid  = threadIdx.x >> 6;
    int qrow = lane & 15;
    int g    = lane >> 4;
    int h = blockIdx.y, b = blockIdx.z;
    int q0 = blockIdx.x * 64 + wid * 16;

    const float scale = 0.17677669529663687f;   // 1/sqrt(32)

    const size_t tq = (size_t)(b * NP + q0 + qrow) * DD + h * HDD;
    bf16x8_t qf = *(const bf16x8_t*)(q + tq + g * 8);

    float m = -1e30f, lsum = 0.f;
    f32x4_t ot0 = {0.f, 0.f, 0.f, 0.f};
    f32x4_t ot1 = {0.f, 0.f, 0.f, 0.f};

    for (int k0 = 0; k0 < NP; k0 += 32) {
        const size_t kb = (size_t)(b * NP + k0 + qrow) * DD + h * HDD + g * 8;
        bf16x8_t kf0 = *(const bf16x8_t*)(k + kb);
        bf16x8_t kf1 = *(const bf16x8_t*)(k + kb + 16 * DD);
        f32x4_t z = {0.f, 0.f, 0.f, 0.f};
        f32x4_t s0 = __builtin_amdgcn_mfma_f32_16x16x32_bf16(kf0, qf, z, 0, 0, 0);
        f32x4_t s1 = __builtin_amdgcn_mfma_f32_16x16x32_bf16(kf1, qf, z, 0, 0, 0);

        float sv[8];
        #pragma unroll
        for (int r = 0; r < 4; r++) { sv[r] = s0[r] * scale; sv[4 + r] = s1[r] * scale; }

        float tmax = fmaxf(fmaxf(fmaxf(sv[0], sv[1]), fmaxf(sv[2], sv[3])),
                           fmaxf(fmaxf(sv[4], sv[5]), fmaxf(sv[6], sv[7])));
        tmax = fmaxf(tmax, __shfl_xor(tmax, 16, 64));
        tmax = fmaxf(tmax, __shfl_xor(tmax, 32, 64));
        float nm = fmaxf(m, tmax);
        float f  = __expf(m - nm);
        lsum *= f;
        #pragma unroll
        for (int r = 0; r < 4; r++) { ot0[r] *= f; ot1[r] *= f; }

        float psum = 0.f;
        ushort pb[8];
        #pragma unroll
        for (int i = 0; i < 8; i++) {
            float p = __expf(sv[i] - nm);
            psum += p;
            pb[i] = f2bf(p);
        }
        psum += __shfl_xor(psum, 16, 64);
        psum += __shfl_xor(psum, 32, 64);
        lsum += psum;
        m = nm;

        *(ushort4*)&P_lds[wid][qrow][g * 4]      = make_ushort4(pb[0], pb[1], pb[2], pb[3]);
        *(ushort4*)&P_lds[wid][qrow][16 + g * 4] = make_ushort4(pb[4], pb[5], pb[6], pb[7]);
        bf16x8_t pf = *(const bf16x8_t*)&P_lds[wid][qrow][g * 8];

        const ushort* vp = v + (size_t)(b * NP + k0) * DD + h * HDD;
        bf16x8_t va0, va1;
        #pragma unroll
        for (int j = 0; j < 8; j++) {
            const ushort* vr = vp + (size_t)(g * 8 + j) * DD;
            va0[j] = (short)vr[qrow];
            va1[j] = (short)vr[16 + qrow];
        }
        ot0 = __builtin_amdgcn_mfma_f32_16x16x32_bf16(va0, pf, ot0, 0, 0, 0);
        ot1 = __builtin_amdgcn_mfma_f32_16x16x32_bf16(va1, pf, ot1, 0, 0, 0);
    }

    float inv = 1.f / lsum;
    ushort4 r0 = make_ushort4(f2bf(ot0[0] * inv), f2bf(ot0[1] * inv),
                              f2bf(ot0[2] * inv), f2bf(ot0[3] * inv));
    ushort4 r1 = make_ushort4(f2bf(ot1[0] * inv), f2bf(ot1[1] * inv),
                              f2bf(ot1[2] * inv), f2bf(ot1[3] * inv));
    *(ushort4*)(o + tq + g * 4)      = r0;
    *(ushort4*)(o + tq + 16 + g * 4) = r1;
}

// ---------------------------------------------------------------------------
// Head layer 2: out = t1(bf16) @ w2(f32) + b2, scattered to [B,NA,H,W,S].
// ---------------------------------------------------------------------------
__global__ __launch_bounds__(256) void head2_kernel(
        const ushort* __restrict__ t1, const float* __restrict__ w2,
        const float* __restrict__ b2, float* __restrict__ out,
        int ncols, int S)
{
    __shared__ float row[DD];
    int token = blockIdx.x;
    int c = threadIdx.x;
    row[c] = bf2f(t1[(size_t)token * DD + c]);
    __syncthreads();
    if (c < ncols) {
        float sum = b2[c];
        #pragma unroll 8
        for (int kk = 0; kk < DD; kk++) sum += row[kk] * w2[kk * ncols + c];
        int a  = c / S;
        int s  = c - a * S;
        int b  = token / NP;
        int hw = token - b * NP;
        out[((size_t)(b * NA + a) * NP + hw) * S + s] = sum;
    }
}

// ---------------------------------------------------------------------------
static inline void launch_gemm(const ushort* A, const ushort* Bt, const float* bias,
                               const float* bias2, const float* res, float* Cf,
                               ushort* Cbf, int M, int N, int K, int relu,
                               hipStream_t s) {
    dim3 g(N / 64, M / 64), b(256);
    hipLaunchKernelGGL(gemm_mfma_kernel, g, b, 0, s,
                       A, Bt, bias, bias2, res, Cf, Cbf, M, N, K, relu);
}

extern "C" void kernel_launch(void* const* d_in, const int* in_sizes, int n_in,
                              void* d_out, int out_size, void* d_ws, size_t ws_size,
                              hipStream_t stream) {
    const float* x      = (const float*)d_in[0];
    const float* conv_w = (const float*)d_in[1];
    const float* conv_b = (const float*)d_in[2];
    const float* pos    = (const float*)d_in[3];
    const float* qw     = (const float*)d_in[4];
    const float* qb     = (const float*)d_in[5];
    const float* kw     = (const float*)d_in[6];
    const float* kb     = (const float*)d_in[7];
    const float* vw     = (const float*)d_in[8];
    const float* vb     = (const float*)d_in[9];
    const float* pw     = (const float*)d_in[10];
    const float* pb     = (const float*)d_in[11];
    const float* ln1s   = (const float*)d_in[12];
    const float* ln1b   = (const float*)d_in[13];
    const float* ln2s   = (const float*)d_in[14];
    const float* ln2b   = (const float*)d_in[15];
    const float* f1w    = (const float*)d_in[16];
    const float* f1b    = (const float*)d_in[17];
    const float* f2w    = (const float*)d_in[18];
    const float* f2b    = (const float*)d_in[19];
    const float* cls_w1 = (const float*)d_in[20];
    const float* cls_b1 = (const float*)d_in[21];
    const float* cls_w2 = (const float*)d_in[22];
    const float* cls_b2 = (const float*)d_in[23];
    const float* box_w1 = (const float*)d_in[24];
    const float* box_b1 = (const float*)d_in[25];
    const float* box_w2 = (const float*)d_in[26];
    const float* box_b2 = (const float*)d_in[27];
    const float* obj_w1 = (const float*)d_in[28];
    const float* obj_b1 = (const float*)d_in[29];
    const float* obj_w2 = (const float*)d_in[30];
    const float* obj_b2 = (const float*)d_in[31];

    float* out = (float*)d_out;
    const size_t TD = (size_t)TT * DD;   // 1,638,400

    // byte-based workspace layout
    char* p = (char*)d_ws;
    auto alloc = [&](size_t bytes) { char* r = p; p += (bytes + 255) & ~(size_t)255; return r; };
    float*  h    = (float*) alloc(TD * 4);
    ushort* y    = (ushort*)alloc(TD * 2);
    ushort* qB   = (ushort*)alloc(TD * 2);
    ushort* kB   = (ushort*)alloc(TD * 2);
    ushort* vB   = (ushort*)alloc(TD * 2);
    ushort* oB   = (ushort*)alloc(TD * 2);
    ushort* hbf  = (ushort*)alloc(TD * 2);
    ushort* t1   = (ushort*)alloc(TD * 2);
    ushort* ffn  = (ushort*)alloc((size_t)TT * FF * 2);
    ushort* xT   = (ushort*)alloc((size_t)TT * CIN * 2);
    ushort* wT   = (ushort*)alloc((size_t)2949120 * 2);

    // transposed-weight sub-buffers (ushort offsets)
    ushort* convT = wT;
    ushort* qwT   = wT + 131072;
    ushort* kwT   = wT + 262144;
    ushort* vwT   = wT + 393216;
    ushort* pwT   = wT + 524288;
    ushort* f1wT  = wT + 655360;
    ushort* f2wT  = wT + 1703936;
    ushort* clsT  = wT + 2752512;
    ushort* boxT  = wT + 2818048;
    ushort* objT  = wT + 2883584;

    // 0) weight prep (transpose + bf16)
    WPrep wp;
    int total_tiles = 0;
    auto setd = [&](int i, const float* src, ushort* dst, int R, int C) {
        wp.d[i] = {src, dst, R, C, (R / 32) * (C / 32)};
        total_tiles += wp.d[i].ntiles;
    };
    setd(0,  conv_w, convT, CIN, DD);
    setd(1,  qw,                 qwT,          DD, DD);
    setd(2,  qw + DD * DD,       qwT + DD * DD, DD, DD);
    setd(3,  kw,                 kwT,          DD, DD);
    setd(4,  kw + DD * DD,       kwT + DD * DD, DD, DD);
    setd(5,  vw,                 vwT,          DD, DD);
    setd(6,  vw + DD * DD,       vwT + DD * DD, DD, DD);
    setd(7,  pw,                 pwT,          DD, DD);
    setd(8,  pw + DD * DD,       pwT + DD * DD, DD, DD);
    setd(9,  f1w,                f1wT,            DD, FF);
    setd(10, f1w + DD * FF,      f1wT + DD * FF,  DD, FF);
    setd(11, f2w,                f2wT,            FF, DD);
    setd(12, f2w + FF * DD,      f2wT + FF * DD,  FF, DD);
    setd(13, cls_w1, clsT, DD, DD);
    setd(14, box_w1, boxT, DD, DD);
    setd(15, obj_w1, objT, DD, DD);
    hipLaunchKernelGGL(wprep_kernel, dim3(total_tiles), dim3(32, 8), 0, stream, wp);

    // 1) x transpose -> [T, CIN] bf16
    hipLaunchKernelGGL(transpose_x_kernel, dim3(CIN / 32, NP / 32, BB), dim3(32, 8),
                       0, stream, x, xT);

    // 2) conv 1x1 projection + conv_b + pos -> h [T, D] f32
    launch_gemm(xT, convT, conv_b, pos, nullptr, h, nullptr, TT, DD, CIN, 0, stream);

    // 3) transformer layers
    for (int i = 0; i < 2; i++) {
        hipLaunchKernelGGL(ln_kernel, dim3(TT), dim3(DD), 0, stream,
                           h, ln1s + i * DD, ln1b + i * DD, y);
        launch_gemm(y, qwT + i * DD * DD, qb + i * DD, nullptr, nullptr,
                    nullptr, qB, TT, DD, DD, 0, stream);
        launch_gemm(y, kwT + i * DD * DD, kb + i * DD, nullptr, nullptr,
                    nullptr, kB, TT, DD, DD, 0, stream);
        launch_gemm(y, vwT + i * DD * DD, vb + i * DD, nullptr, nullptr,
                    nullptr, vB, TT, DD, DD, 0, stream);

        hipLaunchKernelGGL(attn_mfma_kernel, dim3(NP / 64, NHH, BB), dim3(256), 0, stream,
                           qB, kB, vB, oB);

        launch_gemm(oB, pwT + i * DD * DD, pb + i * DD, nullptr, h, h, nullptr,
                    TT, DD, DD, 0, stream);

        hipLaunchKernelGGL(ln_kernel, dim3(TT), dim3(DD), 0, stream,
                           h, ln2s + i * DD, ln2b + i * DD, y);
        launch_gemm(y, f1wT + i * DD * FF, f1b + i * FF, nullptr, nullptr,
                    nullptr, ffn, TT, FF, DD, 1, stream);
        // last FFN2 of last layer writes bf16 h for the heads; earlier writes f32 h
        launch_gemm(ffn, f2wT + i * FF * DD, f2b + i * DD, nullptr, h,
                    (i == 0) ? h : nullptr, (i == 1) ? hbf : nullptr,
                    TT, DD, FF, 0, stream);
    }

    // 4) heads
    float* cls_out = out;
    float* box_out = out + (size_t)BB * NA * NP * NC;
    float* obj_out = box_out + (size_t)BB * NA * NP * 4;

    launch_gemm(hbf, clsT, cls_b1, nullptr, nullptr, nullptr, t1, TT, DD, DD, 1, stream);
    hipLaunchKernelGGL(head2_kernel, dim3(TT), dim3(DD), 0, stream,
                       t1, cls_w2, cls_b2, cls_out, NA * NC, NC);

    launch_gemm(hbf, boxT, box_b1, nullptr, nullptr, nullptr, t1, TT, DD, DD, 1, stream);
    hipLaunchKernelGGL(head2_kernel, dim3(TT), dim3(DD), 0, stream,
                       t1, box_w2, box_b2, box_out, NA * 4, 4);

    launch_gemm(hbf, objT, obj_b1, nullptr, nullptr, nullptr, t1, TT, DD, DD, 1, stream);
    hipLaunchKernelGGL(head2_kernel, dim3(TT), dim3(DD), 0, stream,
                       t1, obj_w2, obj_b2, obj_out, NA * 1, 1);
}